// Round 5
// baseline (405.780 us; speedup 1.0000x reference)
//
#include <hip/hip_runtime.h>
#include <math.h>

typedef unsigned short ushort_t;
typedef __attribute__((ext_vector_type(8))) short bf16x8;
typedef __attribute__((ext_vector_type(4))) float f32x4;

__device__ __forceinline__ ushort_t f2bf(float f) {
  unsigned u = __float_as_uint(f);
  unsigned r = (u + 0x7FFF + ((u >> 16) & 1)) >> 16;  // RNE
  return (ushort_t)r;
}
__device__ __forceinline__ float bf2f(ushort_t u) {
  return __uint_as_float(((unsigned)u) << 16);
}

__device__ __forceinline__ void gload_lds16(const void* g, void* l) {
  __builtin_amdgcn_global_load_lds(
      (const __attribute__((address_space(1))) void*)g,
      (__attribute__((address_space(3))) void*)l, 16, 0, 0);
}

// ---------------------------------------------------------------- init: cursor=1, zero s/d buffers
__global__ void init_k(int* __restrict__ cursor, int n, float* __restrict__ z, int nz) {
  int i = blockIdx.x * blockDim.x + threadIdx.x;
  if (i < n) cursor[i] = 1;  // self-loop contributes 1 to in-degree
  if (i < nz) z[i] = 0.f;
}

__global__ void count_edges_k(const int* __restrict__ dst, int E, int* __restrict__ cnt) {
  int i = blockIdx.x * blockDim.x + threadIdx.x;
  if (i < E) atomicAdd(&cnt[dst[i]], 1);
}

// exclusive scan; writes indptr AND cursor
__global__ void scan_k(const int* __restrict__ cnt, int* __restrict__ indptr,
                       int* __restrict__ cursor, int n) {
  __shared__ int lds[1024];
  __shared__ int carry_s;
  int t = threadIdx.x;
  if (t == 0) carry_s = 0;
  __syncthreads();
  for (int base = 0; base < n; base += 1024) {
    int i = base + t;
    int v = (i < n) ? cnt[i] : 0;
    lds[t] = v;
    __syncthreads();
    for (int off = 1; off < 1024; off <<= 1) {
      int add = (t >= off) ? lds[t - off] : 0;
      __syncthreads();
      lds[t] += add;
      __syncthreads();
    }
    int carry = carry_s;
    if (i < n) { int e = carry + lds[t] - v; indptr[i] = e; cursor[i] = e; }
    __syncthreads();
    if (t == 1023) carry_s = carry + lds[1023];
    __syncthreads();
  }
  if (t == 0) indptr[n] = carry_s;
}

__global__ void scatter_k(const int* __restrict__ src, const int* __restrict__ dst, int E, int n,
                          int* __restrict__ cursor, int* __restrict__ esrc) {
  int i = blockIdx.x * blockDim.x + threadIdx.x;
  if (i < E) {
    int p = atomicAdd(&cursor[dst[i]], 1);
    esrc[p] = src[i];
  } else if (i < E + n) {
    int node = i - E;
    int p = atomicAdd(&cursor[node], 1);
    esrc[p] = node;  // self loop
  }
}

// ---------------------------------------------------------------- conversions
__global__ void cast_bf16_k(const float* __restrict__ in, ushort_t* __restrict__ out, int n4) {
  int i = blockIdx.x * blockDim.x + threadIdx.x;
  if (i < n4) {
    float4 v = ((const float4*)in)[i];
    ushort_t o0 = f2bf(v.x), o1 = f2bf(v.y), o2 = f2bf(v.z), o3 = f2bf(v.w);
    ushort_t* p = out + i * 4;
    p[0] = o0; p[1] = o1; p[2] = o2; p[3] = o3;
  }
}

// Two fp32 [K][Na],[K][Nb] -> one bf16 [Na+Nb][K] (concatenated transpose).
__global__ __launch_bounds__(256) void transpose_dual_k(const float* __restrict__ Wa, int Na,
                                                        const float* __restrict__ Wb, int Nb,
                                                        int K, ushort_t* __restrict__ dst) {
  __shared__ float tile[32][33];
  const int bx = blockIdx.x * 32;  // n dim (global, 0..Na+Nb)
  const int by = blockIdx.y * 32;  // k dim
  const int tx = threadIdx.x & 31, ty = threadIdx.x >> 5;  // 32x8
  const bool isB = bx >= Na;       // blocks are 32-aligned; Na is a multiple of 32
  const float* W = isB ? Wb : Wa;
  const int Nw = isB ? Nb : Na;
  const int nc = bx - (isB ? Na : 0) + tx;
  for (int i = ty; i < 32; i += 8)
    tile[i][tx] = W[(size_t)(by + i) * Nw + nc];
  __syncthreads();
  for (int i = ty; i < 32; i += 8)
    dst[(size_t)(bx + i) * K + by + tx] = f2bf(tile[tx][i]);
}

// Fold a3 into W3cat pad rows: row 448+hd = W3 . a3s[hd], row 454+hd = W3 . a3d[hd].
// Rows 460..511 zeroed. s3 = h3.a3s == act @ (W3.a3s) so the GEMM emits logits directly.
__global__ void fold_a3_k(const float* __restrict__ W3, const float* __restrict__ a3s,
                          const float* __restrict__ a3d, ushort_t* __restrict__ W3cat) {
  int k = blockIdx.x * blockDim.x + threadIdx.x;  // 0..1023
  if (k >= 1024) return;
  const float* row = W3 + (size_t)k * 384;
  for (int hd = 0; hd < 6; ++hd) {
    float ss = 0.f, dd = 0.f;
    for (int c = 0; c < 64; ++c) {
      float w = row[hd * 64 + c];
      ss += w * a3s[hd * 64 + c];
      dd += w * a3d[hd * 64 + c];
    }
    W3cat[(size_t)(448 + hd) * 1024 + k] = f2bf(ss);
    W3cat[(size_t)(454 + hd) * 1024 + k] = f2bf(dd);
  }
  for (int j = 460; j < 512; ++j) W3cat[(size_t)j * 1024 + k] = 0;
}

// ---------------------------------------------------------------- fused MFMA GEMM (LDS double-buffer)
// A[M,K](bf16) @ Bcat[NCT,K]^T. Cols [0,HC) -> h_out (bf16). Cols [HC,HC+SC) -> skip_out
// (+skip_bias). If SD_COLS: cols [HC+SC, HC+SC+12) -> sb/db direct (H=6 layout).
// If LOGITS: per-row s,d (H=4,C=256) reduced from acc and atomically accumulated.
template<int NCT, int HC, int SC, bool LOGITS, bool SKIP_BF16, bool SD_COLS>
__global__ __launch_bounds__(256) void gemm_fused(const ushort_t* __restrict__ A,
                                                  const ushort_t* __restrict__ BT,
                                                  const float* __restrict__ skip_bias,
                                                  const float* __restrict__ a_src,
                                                  const float* __restrict__ a_dst,
                                                  float* __restrict__ sb,
                                                  float* __restrict__ db,
                                                  ushort_t* __restrict__ h_out,
                                                  void* __restrict__ skip_out,
                                                  int M, int K) {
  __shared__ ushort_t As[2][128 * 32];
  __shared__ ushort_t Bs[2][128 * 32];
  const int bm = blockIdx.y * 128, bn = blockIdx.x * 128;
  const int t = threadIdx.x;
  const int l = t & 63, wid = t >> 6;
  const int wm = wid >> 1, wn = wid & 1;

  size_t goffA[2], goffB[2];
  for (int i = 0; i < 2; ++i) {
    int seg = wid * 2 + i;
    int row = seg * 16 + (l >> 2);
    int p = l & 3;
    int ls = p ^ ((row >> 1) & 3);  // inverse-swizzled source slot
    int ga = min(bm + row, M - 1);
    int gb = min(bn + row, NCT - 1);
    goffA[i] = (size_t)ga * K + ls * 8;
    goffB[i] = (size_t)gb * K + ls * 8;
  }

  const int lr = l & 15, s = l >> 4;
  int raddrA[4], raddrB[4];
  for (int m = 0; m < 4; ++m) {
    int rowA = wm * 64 + m * 16 + lr;
    raddrA[m] = rowA * 32 + (s ^ ((rowA >> 1) & 3)) * 8;
    int rowB = wn * 64 + m * 16 + lr;
    raddrB[m] = rowB * 32 + (s ^ ((rowB >> 1) & 3)) * 8;
  }

  f32x4 acc[4][4] = {};
  auto stage = [&](int k0, int buf) {
    gload_lds16(A + goffA[0] + k0, &As[buf][(wid * 2 + 0) * 512]);
    gload_lds16(A + goffA[1] + k0, &As[buf][(wid * 2 + 1) * 512]);
    gload_lds16(BT + goffB[0] + k0, &Bs[buf][(wid * 2 + 0) * 512]);
    gload_lds16(BT + goffB[1] + k0, &Bs[buf][(wid * 2 + 1) * 512]);
  };
  auto compute = [&](int buf) {
    bf16x8 a[4], b[4];
#pragma unroll
    for (int m = 0; m < 4; ++m) a[m] = *(const bf16x8*)&As[buf][raddrA[m]];
#pragma unroll
    for (int n = 0; n < 4; ++n) b[n] = *(const bf16x8*)&Bs[buf][raddrB[n]];
#pragma unroll
    for (int m = 0; m < 4; ++m)
#pragma unroll
      for (int n = 0; n < 4; ++n)
        acc[m][n] = __builtin_amdgcn_mfma_f32_16x16x32_bf16(a[m], b[n], acc[m][n], 0, 0, 0);
  };

  // prologue: fill buf0; then each iter prefetches k0 into buf^1 while computing buf.
  stage(0, 0);
  __syncthreads();  // drains vmcnt(0)
  int cur = 0;
  for (int k0 = 32; k0 < K; k0 += 32) {
    stage(k0, cur ^ 1);   // loads in flight during compute below
    compute(cur);
    __syncthreads();      // drains vmcnt(0) + lgkmcnt, one barrier per K-step
    cur ^= 1;
  }
  compute(cur);

  // ---- fused logits (L1/L2): s/d partial = reduce over this wave's 64 cols
  const int colw = bn + wn * 64;  // wave's col base (64-aligned -> single head)
  if (LOGITS && colw < HC) {
    const int head = colw >> 8;
    float as[4], ad[4];
#pragma unroll
    for (int n = 0; n < 4; ++n) {
      int c = (colw + n * 16 + lr) & 255;
      as[n] = a_src[head * 256 + c];
      ad[n] = a_dst[head * 256 + c];
    }
#pragma unroll
    for (int m = 0; m < 4; ++m) {
#pragma unroll
      for (int j = 0; j < 4; ++j) {
        float sp = 0.f, dp = 0.f;
#pragma unroll
        for (int n = 0; n < 4; ++n) { sp += acc[m][n][j] * as[n]; dp += acc[m][n][j] * ad[n]; }
#pragma unroll
        for (int off = 1; off <= 8; off <<= 1) {
          sp += __shfl_xor(sp, off);
          dp += __shfl_xor(dp, off);
        }
        if (lr == 0) {
          int row = bm + wm * 64 + m * 16 + (l >> 4) * 4 + j;
          if (row < M) {
            atomicAdd(&sb[row * 4 + head], sp);
            atomicAdd(&db[row * 4 + head], dp);
          }
        }
      }
    }
  }

  // ---- stores: C/D layout col = lane&15, row = (lane>>4)*4 + j
#pragma unroll
  for (int n = 0; n < 4; ++n) {
    int col = bn + wn * 64 + n * 16 + lr;
    if (col >= HC + SC + (SD_COLS ? 12 : 0)) continue;
    const bool is_h = col < HC;
    const bool is_skip = !is_h && col < HC + SC;
    float bv = is_skip ? skip_bias[col - HC] : 0.f;
#pragma unroll
    for (int m = 0; m < 4; ++m) {
#pragma unroll
      for (int j = 0; j < 4; ++j) {
        int row = bm + wm * 64 + m * 16 + (l >> 4) * 4 + j;
        if (row >= M) continue;
        float v = acc[m][n][j] + bv;
        if (is_h) {
          h_out[(size_t)row * HC + col] = f2bf(v);
        } else if (is_skip) {
          if (SKIP_BF16) ((ushort_t*)skip_out)[(size_t)row * SC + (col - HC)] = f2bf(v);
          else           ((float*)skip_out)[(size_t)row * SC + (col - HC)] = v;
        } else if (SD_COLS) {
          int jj = col - (HC + SC);
          if (jj < 6) sb[row * 6 + jj] = v;
          else        db[row * 6 + (jj - 6)] = v;
        }
      }
    }
  }
}

// ---------------------------------------------------------------- attention + aggregate
template<int H, int C, bool ELU_OUT, bool MEAN_HEADS>
__global__ __launch_bounds__(256) void attn_k(const ushort_t* __restrict__ hfeat,
                                              const float* __restrict__ sbuf,
                                              const float* __restrict__ dbuf,
                                              const int* __restrict__ indptr,
                                              const int* __restrict__ esrc,
                                              const float* __restrict__ bias,
                                              const void* __restrict__ skip_v,
                                              void* __restrict__ out_v) {
  constexpr int F = H * C;
  constexpr int CPT = (F + 255) / 256;   // 4 (F=1024) or 2 (F=384)
  constexpr int CH = 256 / H;            // edge chunk: 64 (H=4), 42 (H=6)
  __shared__ float m_l[H], invden_l[H], d_l[H];
  __shared__ float alpha_l[CH * H];
  __shared__ int src_l[CH];
  __shared__ float accs[MEAN_HEADS ? F : 4];

  const int node = blockIdx.x;
  const int t = threadIdx.x;
  const int beg = indptr[node];
  const int deg = indptr[node + 1] - beg;
  if (t < H) d_l[t] = dbuf[node * H + t];
  __syncthreads();

  const int wave = t >> 6, lane = t & 63;
  for (int hd = wave; hd < H; hd += 4) {
    const float dn = d_l[hd];
    float mx = -1e30f;
    for (int i = lane; i < deg; i += 64) {
      int se = esrc[beg + i];
      float e = sbuf[se * H + hd] + dn;
      e = fmaxf(e, 0.2f * e);  // leaky relu
      mx = fmaxf(mx, e);
    }
    for (int off = 32; off; off >>= 1) mx = fmaxf(mx, __shfl_xor(mx, off));
    float den = 0.f;
    for (int i = lane; i < deg; i += 64) {
      int se = esrc[beg + i];
      float e = sbuf[se * H + hd] + dn;
      e = fmaxf(e, 0.2f * e);
      den += __expf(e - mx);
    }
    for (int off = 32; off; off >>= 1) den += __shfl_xor(den, off);
    if (lane == 0) { m_l[hd] = mx; invden_l[hd] = 1.f / den; }
  }
  __syncthreads();

  float acc[CPT] = {};
  const int c0 = t * CPT;
  const int myhead = c0 / C;
  for (int cb = 0; cb < deg; cb += CH) {
    const int ce = min(CH, deg - cb);
    if (t < ce * H) {
      int e_i = t / H, hd = t % H;
      int se = esrc[beg + cb + e_i];
      if (hd == 0) src_l[e_i] = se;
      float e = sbuf[se * H + hd] + d_l[hd];
      e = fmaxf(e, 0.2f * e);
      alpha_l[e_i * H + hd] = __expf(e - m_l[hd]) * invden_l[hd];
    }
    __syncthreads();
    if (c0 < F) {
      for (int e_i = 0; e_i < ce; ++e_i) {
        int se = src_l[e_i];
        float al = alpha_l[e_i * H + myhead];
        const ushort_t* hp = hfeat + (size_t)se * F + c0;
        if (CPT == 4) {
          ushort4 v = *(const ushort4*)hp;
          acc[0] += al * bf2f(v.x); acc[1] += al * bf2f(v.y);
          acc[2] += al * bf2f(v.z); acc[3] += al * bf2f(v.w);
        } else {
          ushort2 v = *(const ushort2*)hp;
          acc[0] += al * bf2f(v.x); acc[1] += al * bf2f(v.y);
        }
      }
    }
    __syncthreads();
  }

  if (!MEAN_HEADS) {
    if (c0 < F) {
      const ushort_t* skip = (const ushort_t*)skip_v;
      ushort_t* out = (ushort_t*)out_v;
      ushort4 sv = *(const ushort4*)&skip[(size_t)node * F + c0];
      float sk[4] = {bf2f(sv.x), bf2f(sv.y), bf2f(sv.z), bf2f(sv.w)};
      ushort_t r[CPT];
#pragma unroll
      for (int j = 0; j < CPT; ++j) {
        float x = acc[j] + bias[c0 + j] + sk[j];
        if (ELU_OUT) x = x > 0.f ? x : __expf(x) - 1.f;
        r[j] = f2bf(x);
      }
      ushort4 o; o.x = r[0]; o.y = r[1]; o.z = r[2]; o.w = r[3];
      *(ushort4*)&out[(size_t)node * F + c0] = o;
    }
  } else {
    const float* skip = (const float*)skip_v;
    float* out = (float*)out_v;
    if (c0 < F) { accs[c0] = acc[0]; accs[c0 + 1] = acc[1]; }
    __syncthreads();
    if (t < C) {
      float sum = 0.f;
#pragma unroll
      for (int hd = 0; hd < H; ++hd) sum += accs[hd * C + t];
      out[(size_t)node * C + t] = sum * (1.f / (float)H) + bias[t] + skip[(size_t)node * C + t];
    }
  }
}

// ---------------------------------------------------------------- launch
extern "C" void kernel_launch(void* const* d_in, const int* in_sizes, int n_in,
                              void* d_out, int out_size, void* d_ws, size_t ws_size,
                              hipStream_t stream) {
  const float* x      = (const float*)d_in[0];
  const int*   ei     = (const int*)d_in[1];
  const float* W1     = (const float*)d_in[2];
  const float* a1s    = (const float*)d_in[3];
  const float* a1d    = (const float*)d_in[4];
  const float* b1     = (const float*)d_in[5];
  const float* lin1W  = (const float*)d_in[6];
  const float* lin1b  = (const float*)d_in[7];
  const float* W2     = (const float*)d_in[8];
  const float* a2s    = (const float*)d_in[9];
  const float* a2d    = (const float*)d_in[10];
  const float* b2     = (const float*)d_in[11];
  const float* lin2W  = (const float*)d_in[12];
  const float* lin2b  = (const float*)d_in[13];
  const float* W3     = (const float*)d_in[14];
  const float* a3s    = (const float*)d_in[15];
  const float* a3d    = (const float*)d_in[16];
  const float* b3     = (const float*)d_in[17];
  const float* lin3W  = (const float*)d_in[18];
  const float* lin3b  = (const float*)d_in[19];

  const int N = in_sizes[0] / 128;
  const int E = in_sizes[1] / 2;
  const int* src = ei;
  const int* dst = ei + E;

  char* ws = (char*)d_ws;
  size_t off = 0;
  auto alloc = [&](size_t bytes) -> void* {
    void* p = ws + off;
    off += (bytes + 255) & ~(size_t)255;
    return p;
  };
  ushort_t* h_bf    = (ushort_t*)alloc((size_t)N * 1024 * 2);
  ushort_t* skip_bf = (ushort_t*)alloc((size_t)N * 1024 * 2);
  float*    skip3   = (float*)alloc((size_t)N * 64 * 4);
  ushort_t* act_bf  = (ushort_t*)alloc((size_t)N * 1024 * 2);
  ushort_t* x_bf    = (ushort_t*)alloc((size_t)N * 128 * 2);
  ushort_t* W1cat   = (ushort_t*)alloc((size_t)2048 * 128 * 2);
  ushort_t* W2cat   = (ushort_t*)alloc((size_t)2048 * 1024 * 2);
  ushort_t* W3cat   = (ushort_t*)alloc((size_t)512 * 1024 * 2);  // 448..459 folded a3, 460+ zero
  float*    sd12    = (float*)alloc((size_t)4 * N * 4 * 4);      // sb1,db1,sb2,db2 contiguous
  float*    sb1 = sd12, *db1 = sd12 + N * 4, *sb2 = sd12 + 2 * N * 4, *db2 = sd12 + 3 * N * 4;
  float*    sb3     = (float*)alloc((size_t)N * 6 * 4);
  float*    db3     = (float*)alloc((size_t)N * 6 * 4);
  int*      indptr  = (int*)alloc((size_t)(N + 1) * 4);
  int*      cursor  = (int*)alloc((size_t)N * 4);
  int*      esrc    = (int*)alloc((size_t)(E + N) * 4);

  const int NZ = 4 * N * 4;  // floats to zero (sb1,db1,sb2,db2)
  // ---- init (cursor=1 for self loops; zero logit accumulators)
  init_k<<<(max(N, NZ) + 255) / 256, 256, 0, stream>>>(cursor, N, sd12, NZ);
  count_edges_k<<<(E + 255) / 256, 256, 0, stream>>>(dst, E, cursor);
  scan_k<<<1, 1024, 0, stream>>>(cursor, indptr, cursor, N);
  scatter_k<<<(E + N + 255) / 256, 256, 0, stream>>>(src, dst, E, N, cursor, esrc);

  // ---- conversions
  cast_bf16_k<<<(N * 128 / 4 + 255) / 256, 256, 0, stream>>>(x, x_bf, N * 128 / 4);
  transpose_dual_k<<<dim3(64, 4), 256, 0, stream>>>(W1, 1024, lin1W, 1024, 128, W1cat);
  transpose_dual_k<<<dim3(64, 32), 256, 0, stream>>>(W2, 1024, lin2W, 1024, 1024, W2cat);
  transpose_dual_k<<<dim3(14, 32), 256, 0, stream>>>(W3, 384, lin3W, 64, 1024, W3cat);
  fold_a3_k<<<4, 256, 0, stream>>>(W3, a3s, a3d, W3cat);

  const int MB = (N + 127) / 128;
  // ---- Layer 1: fused GEMM (h|skip) + logits atomics
  gemm_fused<2048, 1024, 1024, true, true, false><<<dim3(16, MB), 256, 0, stream>>>(
      x_bf, W1cat, lin1b, a1s, a1d, sb1, db1, h_bf, skip_bf, N, 128);
  attn_k<4, 256, true, false><<<N, 256, 0, stream>>>(h_bf, sb1, db1, indptr, esrc, b1, skip_bf, act_bf);
  // ---- Layer 2
  gemm_fused<2048, 1024, 1024, true, true, false><<<dim3(16, MB), 256, 0, stream>>>(
      act_bf, W2cat, lin2b, a2s, a2d, sb2, db2, h_bf, skip_bf, N, 1024);
  attn_k<4, 256, true, false><<<N, 256, 0, stream>>>(h_bf, sb2, db2, indptr, esrc, b2, skip_bf, act_bf);
  // ---- Layer 3 (H=6, C=64; logits via folded cols 448..459)
  gemm_fused<512, 384, 64, false, false, true><<<dim3(4, MB), 256, 0, stream>>>(
      act_bf, W3cat, lin3b, nullptr, nullptr, sb3, db3, h_bf, skip3, N, 1024);
  attn_k<6, 64, false, true><<<N, 256, 0, stream>>>(h_bf, sb3, db3, indptr, esrc, b3, skip3, d_out);
}

// Round 6
// 405.104 us; speedup vs baseline: 1.0017x; 1.0017x over previous
//
#include <hip/hip_runtime.h>
#include <math.h>

typedef unsigned short ushort_t;
typedef __attribute__((ext_vector_type(8))) short bf16x8;
typedef __attribute__((ext_vector_type(4))) float f32x4;

__device__ __forceinline__ ushort_t f2bf(float f) {
  unsigned u = __float_as_uint(f);
  unsigned r = (u + 0x7FFF + ((u >> 16) & 1)) >> 16;  // RNE
  return (ushort_t)r;
}
__device__ __forceinline__ float bf2f(ushort_t u) {
  return __uint_as_float(((unsigned)u) << 16);
}

__device__ __forceinline__ void gload_lds16(const void* g, void* l) {
  __builtin_amdgcn_global_load_lds(
      (const __attribute__((address_space(1))) void*)g,
      (__attribute__((address_space(3))) void*)l, 16, 0, 0);
}

// counted-vmcnt barrier: wait own staging loads (vmcnt<=N), then sync all waves.
// "memory" clobbers fence compiler reordering of LDS/global ops across the pair.
#define PIPE_BAR(N)                                          \
  do {                                                       \
    asm volatile("s_waitcnt vmcnt(" #N ")" ::: "memory");    \
    __builtin_amdgcn_s_barrier();                            \
    asm volatile("" ::: "memory");                           \
  } while (0)

// ---------------------------------------------------------------- init: cursor=1, zero s/d buffers
__global__ void init_k(int* __restrict__ cursor, int n, float* __restrict__ z, int nz) {
  int i = blockIdx.x * blockDim.x + threadIdx.x;
  if (i < n) cursor[i] = 1;  // self-loop contributes 1 to in-degree
  if (i < nz) z[i] = 0.f;
}

__global__ void count_edges_k(const int* __restrict__ dst, int E, int* __restrict__ cnt) {
  int i = blockIdx.x * blockDim.x + threadIdx.x;
  if (i < E) atomicAdd(&cnt[dst[i]], 1);
}

// exclusive scan; writes indptr AND cursor
__global__ void scan_k(const int* __restrict__ cnt, int* __restrict__ indptr,
                       int* __restrict__ cursor, int n) {
  __shared__ int lds[1024];
  __shared__ int carry_s;
  int t = threadIdx.x;
  if (t == 0) carry_s = 0;
  __syncthreads();
  for (int base = 0; base < n; base += 1024) {
    int i = base + t;
    int v = (i < n) ? cnt[i] : 0;
    lds[t] = v;
    __syncthreads();
    for (int off = 1; off < 1024; off <<= 1) {
      int add = (t >= off) ? lds[t - off] : 0;
      __syncthreads();
      lds[t] += add;
      __syncthreads();
    }
    int carry = carry_s;
    if (i < n) { int e = carry + lds[t] - v; indptr[i] = e; cursor[i] = e; }
    __syncthreads();
    if (t == 1023) carry_s = carry + lds[1023];
    __syncthreads();
  }
  if (t == 0) indptr[n] = carry_s;
}

__global__ void scatter_k(const int* __restrict__ src, const int* __restrict__ dst, int E, int n,
                          int* __restrict__ cursor, int* __restrict__ esrc) {
  int i = blockIdx.x * blockDim.x + threadIdx.x;
  if (i < E) {
    int p = atomicAdd(&cursor[dst[i]], 1);
    esrc[p] = src[i];
  } else if (i < E + n) {
    int node = i - E;
    int p = atomicAdd(&cursor[node], 1);
    esrc[p] = node;  // self loop
  }
}

// ---------------------------------------------------------------- conversions
__global__ void cast_bf16_k(const float* __restrict__ in, ushort_t* __restrict__ out, int n4) {
  int i = blockIdx.x * blockDim.x + threadIdx.x;
  if (i < n4) {
    float4 v = ((const float4*)in)[i];
    ushort_t o0 = f2bf(v.x), o1 = f2bf(v.y), o2 = f2bf(v.z), o3 = f2bf(v.w);
    ushort_t* p = out + i * 4;
    p[0] = o0; p[1] = o1; p[2] = o2; p[3] = o3;
  }
}

// Two fp32 [K][Na],[K][Nb] -> one bf16 [Na+Nb][K] (concatenated transpose).
__global__ __launch_bounds__(256) void transpose_dual_k(const float* __restrict__ Wa, int Na,
                                                        const float* __restrict__ Wb, int Nb,
                                                        int K, ushort_t* __restrict__ dst) {
  __shared__ float tile[32][33];
  const int bx = blockIdx.x * 32;  // n dim (global, 0..Na+Nb)
  const int by = blockIdx.y * 32;  // k dim
  const int tx = threadIdx.x & 31, ty = threadIdx.x >> 5;  // 32x8
  const bool isB = bx >= Na;       // blocks are 32-aligned; Na is a multiple of 32
  const float* W = isB ? Wb : Wa;
  const int Nw = isB ? Nb : Na;
  const int nc = bx - (isB ? Na : 0) + tx;
  for (int i = ty; i < 32; i += 8)
    tile[i][tx] = W[(size_t)(by + i) * Nw + nc];
  __syncthreads();
  for (int i = ty; i < 32; i += 8)
    dst[(size_t)(bx + i) * K + by + tx] = f2bf(tile[tx][i]);
}

// Fold a3 into W3cat pad rows: row 448+hd = W3 . a3s[hd], row 454+hd = W3 . a3d[hd].
// Rows 460..511 zeroed. s3 = h3.a3s == act @ (W3.a3s) so the GEMM emits logits directly.
__global__ void fold_a3_k(const float* __restrict__ W3, const float* __restrict__ a3s,
                          const float* __restrict__ a3d, ushort_t* __restrict__ W3cat) {
  int k = blockIdx.x * blockDim.x + threadIdx.x;  // 0..1023
  if (k >= 1024) return;
  const float* row = W3 + (size_t)k * 384;
  for (int hd = 0; hd < 6; ++hd) {
    float ss = 0.f, dd = 0.f;
    for (int c = 0; c < 64; ++c) {
      float w = row[hd * 64 + c];
      ss += w * a3s[hd * 64 + c];
      dd += w * a3d[hd * 64 + c];
    }
    W3cat[(size_t)(448 + hd) * 1024 + k] = f2bf(ss);
    W3cat[(size_t)(454 + hd) * 1024 + k] = f2bf(dd);
  }
  for (int j = 460; j < 512; ++j) W3cat[(size_t)j * 1024 + k] = 0;
}

// ---------------------------------------------------------------- fused MFMA GEMM
// 4-stage LDS ring, depth-3 prefetch, counted vmcnt + raw barriers (loads span
// barriers; never drained to 0 in steady state). XCD-bijective block swizzle.
// A[M,K](bf16) @ Bcat[NCT,K]^T. Cols [0,HC) -> h_out (bf16). Cols [HC,HC+SC) -> skip_out
// (+skip_bias). If SD_COLS: cols [HC+SC, HC+SC+12) -> sb/db direct (H=6 layout).
// If LOGITS: per-row s,d (H=4,C=256) reduced from acc and atomically accumulated.
template<int NCT, int HC, int SC, bool LOGITS, bool SKIP_BF16, bool SD_COLS>
__global__ __launch_bounds__(256) void gemm_fused(const ushort_t* __restrict__ A,
                                                  const ushort_t* __restrict__ BT,
                                                  const float* __restrict__ skip_bias,
                                                  const float* __restrict__ a_src,
                                                  const float* __restrict__ a_dst,
                                                  float* __restrict__ sb,
                                                  float* __restrict__ db,
                                                  ushort_t* __restrict__ h_out,
                                                  void* __restrict__ skip_out,
                                                  int M, int K) {
  __shared__ ushort_t As[4][128 * 32];  // 32 KB
  __shared__ ushort_t Bs[4][128 * 32];  // 32 KB
  // XCD-aware bijective remap (m204): consecutive orig ids -> same XCD chunk,
  // so the 16 column-blocks sharing an A-panel hit one XCD's L2.
  const int gx = gridDim.x;
  const int nwg = gx * (int)gridDim.y;
  const int orig = blockIdx.y * gx + blockIdx.x;
  const int q = nwg >> 3, r = nwg & 7, xcd = orig & 7;
  const int wgid = (xcd < r ? xcd * (q + 1) : r * (q + 1) + (xcd - r) * q) + (orig >> 3);
  const int bm = (wgid / gx) * 128, bn = (wgid % gx) * 128;

  const int t = threadIdx.x;
  const int l = t & 63, wid = t >> 6;
  const int wm = wid >> 1, wn = wid & 1;

  size_t goffA[2], goffB[2];
  for (int i = 0; i < 2; ++i) {
    int seg = wid * 2 + i;
    int row = seg * 16 + (l >> 2);
    int p = l & 3;
    int ls = p ^ ((row >> 1) & 3);  // inverse-swizzled source slot
    int ga = min(bm + row, M - 1);
    int gb = min(bn + row, NCT - 1);
    goffA[i] = (size_t)ga * K + ls * 8;
    goffB[i] = (size_t)gb * K + ls * 8;
  }

  const int lr = l & 15, s = l >> 4;
  int raddrA[4], raddrB[4];
  for (int m = 0; m < 4; ++m) {
    int rowA = wm * 64 + m * 16 + lr;
    raddrA[m] = rowA * 32 + (s ^ ((rowA >> 1) & 3)) * 8;
    int rowB = wn * 64 + m * 16 + lr;
    raddrB[m] = rowB * 32 + (s ^ ((rowB >> 1) & 3)) * 8;
  }

  f32x4 acc[4][4] = {};
  auto stage = [&](int st) {  // 4 gload_lds instructions per wave = 4 vmcnt units
    int buf = st & 3;
    int k0 = st * 32;
    gload_lds16(A + goffA[0] + k0, &As[buf][(wid * 2 + 0) * 512]);
    gload_lds16(A + goffA[1] + k0, &As[buf][(wid * 2 + 1) * 512]);
    gload_lds16(BT + goffB[0] + k0, &Bs[buf][(wid * 2 + 0) * 512]);
    gload_lds16(BT + goffB[1] + k0, &Bs[buf][(wid * 2 + 1) * 512]);
  };
  auto body = [&](int st) {
    int buf = st & 3;
    bf16x8 a[4], b[4];
#pragma unroll
    for (int m = 0; m < 4; ++m) a[m] = *(const bf16x8*)&As[buf][raddrA[m]];
#pragma unroll
    for (int n = 0; n < 4; ++n) b[n] = *(const bf16x8*)&Bs[buf][raddrB[n]];
#pragma unroll
    for (int m = 0; m < 4; ++m)
#pragma unroll
      for (int n = 0; n < 4; ++n)
        acc[m][n] = __builtin_amdgcn_mfma_f32_16x16x32_bf16(a[m], b[n], acc[m][n], 0, 0, 0);
  };

  const int T = K >> 5;  // K-steps of 32 (>= 4 for all our K)
  stage(0); stage(1); stage(2);
  int st = 0;
  for (; st < T - 3; ++st) {
    PIPE_BAR(8);     // stage st landed everywhere; st+1, st+2 still in flight
    body(st);
    stage(st + 3);   // overwrites slot (st-1)&3: consumed before barrier above
  }
  PIPE_BAR(8); body(T - 3);
  PIPE_BAR(4); body(T - 2);
  PIPE_BAR(0); body(T - 1);

  // ---- fused logits (L1/L2): s/d partial = reduce over this wave's 64 cols
  const int colw = bn + wn * 64;  // wave's col base (64-aligned -> single head)
  if (LOGITS && colw < HC) {
    const int head = colw >> 8;
    float as[4], ad[4];
#pragma unroll
    for (int n = 0; n < 4; ++n) {
      int c = (colw + n * 16 + lr) & 255;
      as[n] = a_src[head * 256 + c];
      ad[n] = a_dst[head * 256 + c];
    }
#pragma unroll
    for (int m = 0; m < 4; ++m) {
#pragma unroll
      for (int j = 0; j < 4; ++j) {
        float sp = 0.f, dp = 0.f;
#pragma unroll
        for (int n = 0; n < 4; ++n) { sp += acc[m][n][j] * as[n]; dp += acc[m][n][j] * ad[n]; }
#pragma unroll
        for (int off = 1; off <= 8; off <<= 1) {
          sp += __shfl_xor(sp, off);
          dp += __shfl_xor(dp, off);
        }
        if (lr == 0) {
          int row = bm + wm * 64 + m * 16 + (l >> 4) * 4 + j;
          if (row < M) {
            atomicAdd(&sb[row * 4 + head], sp);
            atomicAdd(&db[row * 4 + head], dp);
          }
        }
      }
    }
  }

  // ---- stores: C/D layout col = lane&15, row = (lane>>4)*4 + j
#pragma unroll
  for (int n = 0; n < 4; ++n) {
    int col = bn + wn * 64 + n * 16 + lr;
    if (col >= HC + SC + (SD_COLS ? 12 : 0)) continue;
    const bool is_h = col < HC;
    const bool is_skip = !is_h && col < HC + SC;
    float bv = is_skip ? skip_bias[col - HC] : 0.f;
#pragma unroll
    for (int m = 0; m < 4; ++m) {
#pragma unroll
      for (int j = 0; j < 4; ++j) {
        int row = bm + wm * 64 + m * 16 + (l >> 4) * 4 + j;
        if (row >= M) continue;
        float v = acc[m][n][j] + bv;
        if (is_h) {
          h_out[(size_t)row * HC + col] = f2bf(v);
        } else if (is_skip) {
          if (SKIP_BF16) ((ushort_t*)skip_out)[(size_t)row * SC + (col - HC)] = f2bf(v);
          else           ((float*)skip_out)[(size_t)row * SC + (col - HC)] = v;
        } else if (SD_COLS) {
          int jj = col - (HC + SC);
          if (jj < 6) sb[row * 6 + jj] = v;
          else        db[row * 6 + (jj - 6)] = v;
        }
      }
    }
  }
}

// ---------------------------------------------------------------- attention + aggregate
template<int H, int C, bool ELU_OUT, bool MEAN_HEADS>
__global__ __launch_bounds__(256) void attn_k(const ushort_t* __restrict__ hfeat,
                                              const float* __restrict__ sbuf,
                                              const float* __restrict__ dbuf,
                                              const int* __restrict__ indptr,
                                              const int* __restrict__ esrc,
                                              const float* __restrict__ bias,
                                              const void* __restrict__ skip_v,
                                              void* __restrict__ out_v) {
  constexpr int F = H * C;
  constexpr int CPT = (F + 255) / 256;   // 4 (F=1024) or 2 (F=384)
  constexpr int CH = 256 / H;            // edge chunk: 64 (H=4), 42 (H=6)
  __shared__ float m_l[H], invden_l[H], d_l[H];
  __shared__ float alpha_l[CH * H];
  __shared__ int src_l[CH];
  __shared__ float accs[MEAN_HEADS ? F : 4];

  const int node = blockIdx.x;
  const int t = threadIdx.x;
  const int beg = indptr[node];
  const int deg = indptr[node + 1] - beg;
  if (t < H) d_l[t] = dbuf[node * H + t];
  __syncthreads();

  const int wave = t >> 6, lane = t & 63;
  for (int hd = wave; hd < H; hd += 4) {
    const float dn = d_l[hd];
    float mx = -1e30f;
    for (int i = lane; i < deg; i += 64) {
      int se = esrc[beg + i];
      float e = sbuf[se * H + hd] + dn;
      e = fmaxf(e, 0.2f * e);  // leaky relu
      mx = fmaxf(mx, e);
    }
    for (int off = 32; off; off >>= 1) mx = fmaxf(mx, __shfl_xor(mx, off));
    float den = 0.f;
    for (int i = lane; i < deg; i += 64) {
      int se = esrc[beg + i];
      float e = sbuf[se * H + hd] + dn;
      e = fmaxf(e, 0.2f * e);
      den += __expf(e - mx);
    }
    for (int off = 32; off; off >>= 1) den += __shfl_xor(den, off);
    if (lane == 0) { m_l[hd] = mx; invden_l[hd] = 1.f / den; }
  }
  __syncthreads();

  float acc[CPT] = {};
  const int c0 = t * CPT;
  const int myhead = c0 / C;
  for (int cb = 0; cb < deg; cb += CH) {
    const int ce = min(CH, deg - cb);
    if (t < ce * H) {
      int e_i = t / H, hd = t % H;
      int se = esrc[beg + cb + e_i];
      if (hd == 0) src_l[e_i] = se;
      float e = sbuf[se * H + hd] + d_l[hd];
      e = fmaxf(e, 0.2f * e);
      alpha_l[e_i * H + hd] = __expf(e - m_l[hd]) * invden_l[hd];
    }
    __syncthreads();
    if (c0 < F) {
      for (int e_i = 0; e_i < ce; ++e_i) {
        int se = src_l[e_i];
        float al = alpha_l[e_i * H + myhead];
        const ushort_t* hp = hfeat + (size_t)se * F + c0;
        if (CPT == 4) {
          ushort4 v = *(const ushort4*)hp;
          acc[0] += al * bf2f(v.x); acc[1] += al * bf2f(v.y);
          acc[2] += al * bf2f(v.z); acc[3] += al * bf2f(v.w);
        } else {
          ushort2 v = *(const ushort2*)hp;
          acc[0] += al * bf2f(v.x); acc[1] += al * bf2f(v.y);
        }
      }
    }
    __syncthreads();
  }

  if (!MEAN_HEADS) {
    if (c0 < F) {
      const ushort_t* skip = (const ushort_t*)skip_v;
      ushort_t* out = (ushort_t*)out_v;
      ushort4 sv = *(const ushort4*)&skip[(size_t)node * F + c0];
      float sk[4] = {bf2f(sv.x), bf2f(sv.y), bf2f(sv.z), bf2f(sv.w)};
      ushort_t r[CPT];
#pragma unroll
      for (int j = 0; j < CPT; ++j) {
        float x = acc[j] + bias[c0 + j] + sk[j];
        if (ELU_OUT) x = x > 0.f ? x : __expf(x) - 1.f;
        r[j] = f2bf(x);
      }
      ushort4 o; o.x = r[0]; o.y = r[1]; o.z = r[2]; o.w = r[3];
      *(ushort4*)&out[(size_t)node * F + c0] = o;
    }
  } else {
    const float* skip = (const float*)skip_v;
    float* out = (float*)out_v;
    if (c0 < F) { accs[c0] = acc[0]; accs[c0 + 1] = acc[1]; }
    __syncthreads();
    if (t < C) {
      float sum = 0.f;
#pragma unroll
      for (int hd = 0; hd < H; ++hd) sum += accs[hd * C + t];
      out[(size_t)node * C + t] = sum * (1.f / (float)H) + bias[t] + skip[(size_t)node * C + t];
    }
  }
}

// ---------------------------------------------------------------- launch
extern "C" void kernel_launch(void* const* d_in, const int* in_sizes, int n_in,
                              void* d_out, int out_size, void* d_ws, size_t ws_size,
                              hipStream_t stream) {
  const float* x      = (const float*)d_in[0];
  const int*   ei     = (const int*)d_in[1];
  const float* W1     = (const float*)d_in[2];
  const float* a1s    = (const float*)d_in[3];
  const float* a1d    = (const float*)d_in[4];
  const float* b1     = (const float*)d_in[5];
  const float* lin1W  = (const float*)d_in[6];
  const float* lin1b  = (const float*)d_in[7];
  const float* W2     = (const float*)d_in[8];
  const float* a2s    = (const float*)d_in[9];
  const float* a2d    = (const float*)d_in[10];
  const float* b2     = (const float*)d_in[11];
  const float* lin2W  = (const float*)d_in[12];
  const float* lin2b  = (const float*)d_in[13];
  const float* W3     = (const float*)d_in[14];
  const float* a3s    = (const float*)d_in[15];
  const float* a3d    = (const float*)d_in[16];
  const float* b3     = (const float*)d_in[17];
  const float* lin3W  = (const float*)d_in[18];
  const float* lin3b  = (const float*)d_in[19];

  const int N = in_sizes[0] / 128;
  const int E = in_sizes[1] / 2;
  const int* src = ei;
  const int* dst = ei + E;

  char* ws = (char*)d_ws;
  size_t off = 0;
  auto alloc = [&](size_t bytes) -> void* {
    void* p = ws + off;
    off += (bytes + 255) & ~(size_t)255;
    return p;
  };
  ushort_t* h_bf    = (ushort_t*)alloc((size_t)N * 1024 * 2);
  ushort_t* skip_bf = (ushort_t*)alloc((size_t)N * 1024 * 2);
  float*    skip3   = (float*)alloc((size_t)N * 64 * 4);
  ushort_t* act_bf  = (ushort_t*)alloc((size_t)N * 1024 * 2);
  ushort_t* x_bf    = (ushort_t*)alloc((size_t)N * 128 * 2);
  ushort_t* W1cat   = (ushort_t*)alloc((size_t)2048 * 128 * 2);
  ushort_t* W2cat   = (ushort_t*)alloc((size_t)2048 * 1024 * 2);
  ushort_t* W3cat   = (ushort_t*)alloc((size_t)512 * 1024 * 2);  // 448..459 folded a3, 460+ zero
  float*    sd12    = (float*)alloc((size_t)4 * N * 4 * 4);      // sb1,db1,sb2,db2 contiguous
  float*    sb1 = sd12, *db1 = sd12 + N * 4, *sb2 = sd12 + 2 * N * 4, *db2 = sd12 + 3 * N * 4;
  float*    sb3     = (float*)alloc((size_t)N * 6 * 4);
  float*    db3     = (float*)alloc((size_t)N * 6 * 4);
  int*      indptr  = (int*)alloc((size_t)(N + 1) * 4);
  int*      cursor  = (int*)alloc((size_t)N * 4);
  int*      esrc    = (int*)alloc((size_t)(E + N) * 4);

  const int NZ = 4 * N * 4;  // floats to zero (sb1,db1,sb2,db2)
  // ---- init (cursor=1 for self loops; zero logit accumulators)
  init_k<<<(max(N, NZ) + 255) / 256, 256, 0, stream>>>(cursor, N, sd12, NZ);
  count_edges_k<<<(E + 255) / 256, 256, 0, stream>>>(dst, E, cursor);
  scan_k<<<1, 1024, 0, stream>>>(cursor, indptr, cursor, N);
  scatter_k<<<(E + N + 255) / 256, 256, 0, stream>>>(src, dst, E, N, cursor, esrc);

  // ---- conversions
  cast_bf16_k<<<(N * 128 / 4 + 255) / 256, 256, 0, stream>>>(x, x_bf, N * 128 / 4);
  transpose_dual_k<<<dim3(64, 4), 256, 0, stream>>>(W1, 1024, lin1W, 1024, 128, W1cat);
  transpose_dual_k<<<dim3(64, 32), 256, 0, stream>>>(W2, 1024, lin2W, 1024, 1024, W2cat);
  transpose_dual_k<<<dim3(14, 32), 256, 0, stream>>>(W3, 384, lin3W, 64, 1024, W3cat);
  fold_a3_k<<<4, 256, 0, stream>>>(W3, a3s, a3d, W3cat);

  const int MB = (N + 127) / 128;
  // ---- Layer 1: fused GEMM (h|skip) + logits atomics
  gemm_fused<2048, 1024, 1024, true, true, false><<<dim3(16, MB), 256, 0, stream>>>(
      x_bf, W1cat, lin1b, a1s, a1d, sb1, db1, h_bf, skip_bf, N, 128);
  attn_k<4, 256, true, false><<<N, 256, 0, stream>>>(h_bf, sb1, db1, indptr, esrc, b1, skip_bf, act_bf);
  // ---- Layer 2
  gemm_fused<2048, 1024, 1024, true, true, false><<<dim3(16, MB), 256, 0, stream>>>(
      act_bf, W2cat, lin2b, a2s, a2d, sb2, db2, h_bf, skip_bf, N, 1024);
  attn_k<4, 256, true, false><<<N, 256, 0, stream>>>(h_bf, sb2, db2, indptr, esrc, b2, skip_bf, act_bf);
  // ---- Layer 3 (H=6, C=64; logits via folded cols 448..459)
  gemm_fused<512, 384, 64, false, false, true><<<dim3(4, MB), 256, 0, stream>>>(
      act_bf, W3cat, lin3b, nullptr, nullptr, sb3, db3, h_bf, skip3, N, 1024);
  attn_k<6, 64, false, true><<<N, 256, 0, stream>>>(h_bf, sb3, db3, indptr, esrc, b3, skip3, d_out);
}